// Round 3
// baseline (172.966 us; speedup 1.0000x reference)
//
#include <hip/hip_runtime.h>
#include <hip/hip_bf16.h>
#include <stdint.h>

typedef _Float16 half8 __attribute__((ext_vector_type(8)));
typedef _Float16 half4 __attribute__((ext_vector_type(4)));
typedef float f32x4 __attribute__((ext_vector_type(4)));
typedef unsigned long long u64;

#define N_ROWS 4096
#define DIM 1024
#define KCLS 32
#define MARGIN_F 0.3f
#define SENTN 0xFFFFFFFFFFFFFFFFull

// ---------------- global -> LDS direct staging (16B per lane) ----------------
typedef const __attribute__((address_space(1))) void GASV;
typedef __attribute__((address_space(3))) void LASV;

__device__ __forceinline__ void gload_lds16(const void* g, void* l) {
    __builtin_amdgcn_global_load_lds((GASV*)g, (LASV*)l, 16, 0, 0);
}

// ---------------- prep: sq, f16 convert, prediction argmax ----------------
__global__ __launch_bounds__(256) void prep_kernel(
    const float* __restrict__ inputs, const float* __restrict__ prediction,
    _Float16* __restrict__ xh, float* __restrict__ sq, int* __restrict__ pred_cls)
{
    int wid = threadIdx.x >> 6, lane = threadIdx.x & 63;
    int r = blockIdx.x * 4 + wid;
    const float* row = inputs + (size_t)r * DIM;
    _Float16* hrow = xh + (size_t)r * DIM;
    float s = 0.f;
#pragma unroll
    for (int c = 0; c < 4; ++c) {
        int idx = lane * 4 + c * 256;
        float4 v = *(const float4*)(row + idx);
        s += v.x * v.x + v.y * v.y + v.z * v.z + v.w * v.w;
        half4 h;
        h.x = (_Float16)v.x; h.y = (_Float16)v.y;
        h.z = (_Float16)v.z; h.w = (_Float16)v.w;
        *(half4*)(hrow + idx) = h;
    }
#pragma unroll
    for (int off = 32; off; off >>= 1) s += __shfl_xor(s, off);

    u64 key = 0ull;
    if (lane < KCLS) {
        unsigned b = __float_as_uint(prediction[(size_t)r * KCLS + lane]);
        unsigned u = (b & 0x80000000u) ? ~b : (b | 0x80000000u);
        key = ((u64)u << 32) | (unsigned)(KCLS - 1 - lane);
    }
#pragma unroll
    for (int off = 32; off; off >>= 1) {
        u64 o = __shfl_xor(key, off);
        if (o > key) key = o;
    }
    if (lane == 0) {
        sq[r] = s;
        pred_cls[r] = KCLS - 1 - (int)(key & 0xFFFFFFFFu);
    }
}

// ---------------- f16 MFMA GEMM ----------------
__global__ __launch_bounds__(256) void gemm_kernel(
    const _Float16* __restrict__ X, float* __restrict__ out, int rb0)
{
    __shared__ __align__(16) _Float16 As[128 * 32];
    __shared__ __align__(16) _Float16 Bs[128 * 32];
    int tid = threadIdx.x;
    int bx = blockIdx.x, by = blockIdx.y;
    int srow = tid >> 2;
    int scol = (tid & 3) * 8;
    const _Float16* gA0 = X + (size_t)(rb0 + bx * 128 + srow) * DIM + scol;
    const _Float16* gB0 = X + (size_t)(by * 128 + srow) * DIM + scol;
    const _Float16* gA1 = gA0 + (size_t)64 * DIM;
    const _Float16* gB1 = gB0 + (size_t)64 * DIM;
    _Float16* lA0 = As + tid * 8;
    _Float16* lA1 = As + 64 * 32 + tid * 8;
    _Float16* lB0 = Bs + tid * 8;
    _Float16* lB1 = Bs + 64 * 32 + tid * 8;

    int wid = tid >> 6, lane = tid & 63;
    int wr = (wid >> 1) * 64, wc = (wid & 1) * 64;
    int fr = lane & 15, fk = (lane >> 4) * 8;

    f32x4 acc[4][4];
#pragma unroll
    for (int m = 0; m < 4; ++m)
#pragma unroll
        for (int n = 0; n < 4; ++n) acc[m][n] = (f32x4){0.f, 0.f, 0.f, 0.f};

    for (int k0 = 0; k0 < DIM; k0 += 32) {
        gload_lds16(gA0 + k0, lA0);
        gload_lds16(gA1 + k0, lA1);
        gload_lds16(gB0 + k0, lB0);
        gload_lds16(gB1 + k0, lB1);
        __syncthreads();
        half8 a[4], b[4];
#pragma unroll
        for (int m = 0; m < 4; ++m) a[m] = *(const half8*)(As + (wr + m * 16 + fr) * 32 + fk);
#pragma unroll
        for (int n = 0; n < 4; ++n) b[n] = *(const half8*)(Bs + (wc + n * 16 + fr) * 32 + fk);
#pragma unroll
        for (int m = 0; m < 4; ++m)
#pragma unroll
            for (int n = 0; n < 4; ++n)
                acc[m][n] = __builtin_amdgcn_mfma_f32_16x16x32_f16(a[m], b[n], acc[m][n], 0, 0, 0);
        __syncthreads();
    }
    int orow_base = bx * 128 + wr + (lane >> 4) * 4;
    int ocol_base = by * 128 + wc + fr;
#pragma unroll
    for (int m = 0; m < 4; ++m)
#pragma unroll
        for (int n = 0; n < 4; ++n)
#pragma unroll
            for (int q = 0; q < 4; ++q)
                out[(size_t)(orow_base + m * 16 + q) * N_ROWS + (ocol_base + n * 16)] = acc[m][n][q];
}

// ---------------- per-(row,split) partial top-k (exact) ----------------
// grid = RB*4 blocks; block b: row rloc = b>>2, split = b&3, cols [split*1024, +1024)
__global__ __launch_bounds__(256) void select_part_kernel(
    const float* __restrict__ dot, const float* __restrict__ sq,
    const int* __restrict__ targets, int rb0,
    u64* __restrict__ negC, u64* __restrict__ posC)
{
    __shared__ u64 Tn[4], Tp[4];
    __shared__ u64 negCand[256];
    __shared__ u64 posCand[256];
    __shared__ unsigned cnts[2];
    __shared__ u64 bcast;
    __shared__ u64 red[4];

    int t = threadIdx.x, lane = t & 63, w = t >> 6;
    int rloc = blockIdx.x >> 2, split = blockIdx.x & 3;
    int r = rb0 + rloc;
    int tr = targets[r];
    float sqr = sq[r];
    const float* drow = dot + (size_t)rloc * N_ROWS;
    int col0 = split * 1024 + t * 4;

    negCand[t] = SENTN;
    posCand[t] = 0ull;
    if (t < 2) cnts[t] = 0u;

    // phase 1: one float4 pass, keys in registers
    float4 dv = *(const float4*)(drow + col0);
    float4 sv = *(const float4*)(sq + col0);
    int4 tv = *(const int4*)(targets + col0);
    u64 nk[4], pk[4];
    {
        float d2;
        unsigned bits;
        d2 = fmaxf(sqr + sv.x - 2.f * dv.x, 1e-12f); bits = __float_as_uint(d2);
        nk[0] = (tv.x == tr) ? SENTN : (((u64)bits << 32) | (unsigned)(col0 + 0));
        pk[0] = (tv.x == tr) ? (((u64)bits << 32) | (unsigned)(N_ROWS - 1 - (col0 + 0))) : 0ull;
        d2 = fmaxf(sqr + sv.y - 2.f * dv.y, 1e-12f); bits = __float_as_uint(d2);
        nk[1] = (tv.y == tr) ? SENTN : (((u64)bits << 32) | (unsigned)(col0 + 1));
        pk[1] = (tv.y == tr) ? (((u64)bits << 32) | (unsigned)(N_ROWS - 1 - (col0 + 1))) : 0ull;
        d2 = fmaxf(sqr + sv.z - 2.f * dv.z, 1e-12f); bits = __float_as_uint(d2);
        nk[2] = (tv.z == tr) ? SENTN : (((u64)bits << 32) | (unsigned)(col0 + 2));
        pk[2] = (tv.z == tr) ? (((u64)bits << 32) | (unsigned)(N_ROWS - 1 - (col0 + 2))) : 0ull;
        d2 = fmaxf(sqr + sv.w - 2.f * dv.w, 1e-12f); bits = __float_as_uint(d2);
        nk[3] = (tv.w == tr) ? SENTN : (((u64)bits << 32) | (unsigned)(col0 + 3));
        pk[3] = (tv.w == tr) ? (((u64)bits << 32) | (unsigned)(N_ROWS - 1 - (col0 + 3))) : 0ull;
    }
    u64 mneg = nk[0];
    mneg = nk[1] < mneg ? nk[1] : mneg;
    mneg = nk[2] < mneg ? nk[2] : mneg;
    mneg = nk[3] < mneg ? nk[3] : mneg;
    u64 mpos = pk[0];
    mpos = pk[1] > mpos ? pk[1] : mpos;
    mpos = pk[2] > mpos ? pk[2] : mpos;
    mpos = pk[3] > mpos ? pk[3] : mpos;

    // phase 2: per-wave 3rd-smallest lane-min / 2nd-largest lane-max
    u64 T3 = SENTN, m = mneg;
#pragma unroll
    for (int rd = 0; rd < 3; ++rd) {
        u64 b = m;
#pragma unroll
        for (int off = 32; off; off >>= 1) {
            u64 o = __shfl_xor(b, off);
            b = o < b ? o : b;
        }
        T3 = b;
        if (m == b) m = SENTN;
    }
    u64 P2 = 0ull, mp = mpos;
#pragma unroll
    for (int rd = 0; rd < 2; ++rd) {
        u64 b = mp;
#pragma unroll
        for (int off = 32; off; off >>= 1) {
            u64 o = __shfl_xor(b, off);
            b = o > b ? o : b;
        }
        P2 = b;
        if (mp == b) mp = 0ull;
    }
    if (lane == 0) { Tn[w] = T3; Tp[w] = P2; }
    __syncthreads();

    u64 Tneg = Tn[0];
    Tneg = Tn[1] > Tneg ? Tn[1] : Tneg;
    Tneg = Tn[2] > Tneg ? Tn[2] : Tneg;
    Tneg = Tn[3] > Tneg ? Tn[3] : Tneg;
    u64 Tpos = Tp[0];
    Tpos = Tp[1] < Tpos ? Tp[1] : Tpos;
    Tpos = Tp[2] < Tpos ? Tp[2] : Tpos;
    Tpos = Tp[3] < Tpos ? Tp[3] : Tpos;

    // phase 3: candidate append (atomics; unique keys -> order-independent result)
#pragma unroll
    for (int j = 0; j < 4; ++j) {
        if (nk[j] <= Tneg) {
            unsigned s = atomicAdd(&cnts[0], 1u);
            if (s < 256u) negCand[s] = nk[j];
        }
        if (pk[j] != 0ull && pk[j] >= Tpos) {
            unsigned s = atomicAdd(&cnts[1], 1u);
            if (s < 256u) posCand[s] = pk[j];
        }
    }
    __syncthreads();

    bool fb = (cnts[0] > 256u) || (cnts[1] > 256u);
    size_t nbase = (size_t)((r << 2) | split) * 12;
    size_t pbase = (size_t)((r << 2) | split) * 7;

    if (!fb) {
        if (w == 0) {
            u64 k0 = negCand[lane], k1 = negCand[lane + 64],
                k2 = negCand[lane + 128], k3 = negCand[lane + 192];
#pragma unroll
            for (int rd = 0; rd < 12; ++rd) {
                u64 b = k0 < k1 ? k0 : k1;
                u64 b2 = k2 < k3 ? k2 : k3;
                b = b2 < b ? b2 : b;
#pragma unroll
                for (int off = 32; off; off >>= 1) {
                    u64 o = __shfl_xor(b, off);
                    b = o < b ? o : b;
                }
                if (lane == 0) negC[nbase + rd] = b;
                if (k0 == b) k0 = SENTN;
                if (k1 == b) k1 = SENTN;
                if (k2 == b) k2 = SENTN;
                if (k3 == b) k3 = SENTN;
            }
        } else if (w == 1) {
            u64 k0 = posCand[lane], k1 = posCand[lane + 64],
                k2 = posCand[lane + 128], k3 = posCand[lane + 192];
#pragma unroll
            for (int rd = 0; rd < 7; ++rd) {
                u64 b = k0 > k1 ? k0 : k1;
                u64 b2 = k2 > k3 ? k2 : k3;
                b = b2 > b ? b2 : b;
#pragma unroll
                for (int off = 32; off; off >>= 1) {
                    u64 o = __shfl_xor(b, off);
                    b = o > b ? o : b;
                }
                if (lane == 0) posC[pbase + rd] = b;
                if (k0 == b) k0 = 0ull;
                if (k1 == b) k1 = 0ull;
                if (k2 == b) k2 = 0ull;
                if (k3 == b) k3 = 0ull;
            }
        }
    } else {
        // exact fallback over register keys (degenerate data only)
        for (int rd = 0; rd < 12; ++rd) {
            u64 best = nk[0];
            best = nk[1] < best ? nk[1] : best;
            best = nk[2] < best ? nk[2] : best;
            best = nk[3] < best ? nk[3] : best;
#pragma unroll
            for (int off = 32; off; off >>= 1) {
                u64 o = __shfl_xor(best, off);
                best = o < best ? o : best;
            }
            if (lane == 0) red[w] = best;
            __syncthreads();
            if (t == 0) {
                u64 b0 = red[0];
                b0 = red[1] < b0 ? red[1] : b0;
                b0 = red[2] < b0 ? red[2] : b0;
                b0 = red[3] < b0 ? red[3] : b0;
                negC[nbase + rd] = b0;
                bcast = b0;
            }
            __syncthreads();
            u64 b0 = bcast;
#pragma unroll
            for (int j = 0; j < 4; ++j)
                if (nk[j] == b0) nk[j] = SENTN;
        }
        for (int rd = 0; rd < 7; ++rd) {
            u64 best = pk[0];
            best = pk[1] > best ? pk[1] : best;
            best = pk[2] > best ? pk[2] : best;
            best = pk[3] > best ? pk[3] : best;
#pragma unroll
            for (int off = 32; off; off >>= 1) {
                u64 o = __shfl_xor(best, off);
                best = o > best ? o : best;
            }
            if (lane == 0) red[w] = best;
            __syncthreads();
            if (t == 0) {
                u64 b0 = red[0];
                b0 = red[1] > b0 ? red[1] : b0;
                b0 = red[2] > b0 ? red[2] : b0;
                b0 = red[3] > b0 ? red[3] : b0;
                posC[pbase + rd] = b0;
                bcast = b0;
            }
            __syncthreads();
            u64 b0 = bcast;
#pragma unroll
            for (int j = 0; j < 4; ++j)
                if (pk[j] == b0) pk[j] = 0ull;
        }
    }
}

// ---------------- per-row merge of 4 sorted runs + case logic ----------------
// one wave per row
__global__ __launch_bounds__(64) void merge_kernel(
    const u64* __restrict__ negC, const u64* __restrict__ posC,
    const int* __restrict__ targets, const float* __restrict__ prob,
    const int* __restrict__ pred_cls, const float* __restrict__ thr_p,
    float* __restrict__ per_term, int* __restrict__ corr_flag)
{
    __shared__ u64 mN[48], mP[28];
    __shared__ u64 sN[12], sP[7];

    int lane = threadIdx.x;
    int r = blockIdx.x;
    float thr = *thr_p;

    if (lane < 48) mN[lane] = negC[(size_t)r * 48 + lane];
    if (lane < 28) mP[lane] = posC[(size_t)r * 28 + lane];
    __syncthreads();

    if (lane == 0) {
        int h0 = 0, h1 = 12, h2 = 24, h3 = 36;
        for (int rd = 0; rd < 12; ++rd) {
            u64 v0 = (h0 < 12) ? mN[h0] : SENTN;
            u64 v1 = (h1 < 24) ? mN[h1] : SENTN;
            u64 v2 = (h2 < 36) ? mN[h2] : SENTN;
            u64 v3 = (h3 < 48) ? mN[h3] : SENTN;
            u64 b = v0; int bs = 0;
            if (v1 < b) { b = v1; bs = 1; }
            if (v2 < b) { b = v2; bs = 2; }
            if (v3 < b) { b = v3; bs = 3; }
            sN[rd] = b;
            if (bs == 0) ++h0; else if (bs == 1) ++h1; else if (bs == 2) ++h2; else ++h3;
        }
        h0 = 0; h1 = 7; h2 = 14; h3 = 21;
        for (int rd = 0; rd < 7; ++rd) {
            u64 v0 = (h0 < 7) ? mP[h0] : 0ull;
            u64 v1 = (h1 < 14) ? mP[h1] : 0ull;
            u64 v2 = (h2 < 21) ? mP[h2] : 0ull;
            u64 v3 = (h3 < 28) ? mP[h3] : 0ull;
            u64 b = v0; int bs = 0;
            if (v1 > b) { b = v1; bs = 1; }
            if (v2 > b) { b = v2; bs = 2; }
            if (v3 > b) { b = v3; bs = 3; }
            sP[rd] = b;
            if (bs == 0) ++h0; else if (bs == 1) ++h1; else if (bs == 2) ++h2; else ++h3;
        }
    }
    __syncthreads();

    // lane-parallel confidence checks (replaces serial dependent-load chain)
    bool confN = false, confP = false;
    if (lane >= 1 && lane <= 10) {
        u64 k = sN[lane];
        if (k != SENTN) {
            int c = ((int)(k & 0xFFFFFFFFull)) & (N_ROWS - 1);
            confN = prob[c] >= thr;
        }
    }
    if (lane >= 33 && lane <= 37) {
        u64 k = sP[lane - 32];
        if (k != 0ull) {
            int c = (N_ROWS - 1 - (int)(k & 0xFFFFFFFFull)) & (N_ROWS - 1);
            confP = prob[c] >= thr;
        }
    }
    u64 balN = __ballot(confN);
    u64 balP = __ballot(confP);

    if (lane == 0) {
        int tr = targets[r];
        u64 sp0 = sP[0], sn0 = sN[0];
        float d_ap = sqrtf(__uint_as_float((unsigned)(sp0 >> 32)));
        float d_an = sqrtf(__uint_as_float((unsigned)(sn0 >> 32)));
        int hp = (N_ROWS - 1 - (int)(sp0 & 0xFFFFFFFFull)) & (N_ROWS - 1);
        int hn = ((int)(sn0 & 0xFFFFFFFFull)) & (N_ROWS - 1);
        bool cp = prob[hp] >= thr;
        bool cn = prob[hn] >= thr;
        bool fn = (pred_cls[hn] == tr);

        float d_nn;
        if (balN) {
            int k = __ffsll((unsigned long long)balN) - 1;   // lane index 1..10
            d_nn = sqrtf(__uint_as_float((unsigned)(sN[k] >> 32)));
        } else {
            d_nn = sqrtf(__uint_as_float((unsigned)(sN[11] >> 32)));
        }
        float d_np;
        if (balP) {
            int k = __ffsll((unsigned long long)balP) - 1 - 32;   // 1..5
            d_np = sqrtf(__uint_as_float((unsigned)(sP[k] >> 32)));
        } else {
            d_np = sqrtf(__uint_as_float((unsigned)(sP[6] >> 32)));
        }
        float e1p = __expf(d_ap), e2p = __expf(d_an);
        float w1 = (e1p * d_ap + e2p * d_an) / (e1p + e2p);
        float e1n = __expf(-d_ap), e2n = __expf(-d_an);
        float w0 = (e1n * d_ap + e2n * d_an) / (e1n + e2n + 1e-6f);
        bool case_b = cp && !cn && fn;
        bool case_cd = !cp && (cn || !fn);
        bool inv = !cp && !cn && fn;
        float ap = case_b ? w1 : (case_cd ? d_np : d_ap);
        float an = case_b ? d_nn : (case_cd ? w0 : d_an);
        float per = inv ? fmaxf(an - ap + MARGIN_F, 0.f)
                        : fmaxf(ap - an + MARGIN_F, 0.f);
        per_term[r] = per;
        corr_flag[r] = (an >= ap) ? 1 : 0;
    }
}

// ---------------- final deterministic reduction ----------------
__global__ __launch_bounds__(256) void finalize_kernel(
    const float* __restrict__ per_term, const int* __restrict__ corr_flag,
    const float* __restrict__ prob, const float* __restrict__ thr_p,
    float* __restrict__ out)
{
    __shared__ float sred[4]; __shared__ int cred[4]; __shared__ int nred[4];
    float thr = *thr_p;
    int t = threadIdx.x, lane = t & 63, wid = t >> 6;
    float s = 0.f; int c = 0, n = 0;
    for (int i = t; i < N_ROWS; i += 256) {
        if (prob[i] >= thr) {
            s += per_term[i];
            c += corr_flag[i];
            n += 1;
        }
    }
#pragma unroll
    for (int off = 32; off; off >>= 1) {
        s += __shfl_xor(s, off);
        c += __shfl_xor(c, off);
        n += __shfl_xor(n, off);
    }
    if (lane == 0) { sred[wid] = s; cred[wid] = c; nred[wid] = n; }
    __syncthreads();
    if (t == 0) {
        float ss = sred[0] + sred[1] + sred[2] + sred[3];
        int cc = cred[0] + cred[1] + cred[2] + cred[3];
        int nn = nred[0] + nred[1] + nred[2] + nred[3];
        float loss = (nn > 0) ? ss / (float)nn : 0.f;
        out[0] = loss;
        out[1] = (float)cc;
        out[2] = (float)nn;
    }
}

// ---------------- launch ----------------
extern "C" void kernel_launch(void* const* d_in, const int* in_sizes, int n_in,
                              void* d_out, int out_size, void* d_ws, size_t ws_size,
                              hipStream_t stream)
{
    const float* inputs     = (const float*)d_in[0];
    const float* prediction = (const float*)d_in[1];
    const int*   targets    = (const int*)d_in[2];
    const float* prob       = (const float*)d_in[4];
    const float* thr        = (const float*)d_in[5];
    float* out = (float*)d_out;

    char* ws = (char*)d_ws;
    size_t off = 0;
    auto alloc = [&](size_t bytes) -> char* {
        char* p = ws + off;
        off = (off + bytes + 255) & ~(size_t)255;
        return p;
    };
    _Float16* xh     = (_Float16*)alloc((size_t)N_ROWS * DIM * sizeof(_Float16));
    float* sq        = (float*)alloc((size_t)N_ROWS * 4);
    int*   pred_cls  = (int*)alloc((size_t)N_ROWS * 4);
    float* per_term  = (float*)alloc((size_t)N_ROWS * 4);
    int*   corr_flag = (int*)alloc((size_t)N_ROWS * 4);
    u64*   negC      = (u64*)alloc((size_t)N_ROWS * 48 * 8);
    u64*   posC      = (u64*)alloc((size_t)N_ROWS * 28 * 8);

    size_t avail = (ws_size > off) ? (ws_size - off) : 0;
    size_t rowbytes = (size_t)N_ROWS * 4;
    int RB = 128;
    while (RB * 2 <= N_ROWS && (size_t)(RB * 2) * rowbytes <= avail) RB *= 2;
    float* dotbuf = (float*)alloc((size_t)RB * rowbytes);

    hipLaunchKernelGGL(prep_kernel, dim3(N_ROWS / 4), dim3(256), 0, stream,
                       inputs, prediction, xh, sq, pred_cls);
    for (int rb0 = 0; rb0 < N_ROWS; rb0 += RB) {
        hipLaunchKernelGGL(gemm_kernel, dim3(RB / 128, N_ROWS / 128), dim3(256), 0, stream,
                           xh, dotbuf, rb0);
        hipLaunchKernelGGL(select_part_kernel, dim3(RB * 4), dim3(256), 0, stream,
                           dotbuf, sq, targets, rb0, negC, posC);
    }
    hipLaunchKernelGGL(merge_kernel, dim3(N_ROWS), dim3(64), 0, stream,
                       negC, posC, targets, prob, pred_cls, thr,
                       per_term, corr_flag);
    hipLaunchKernelGGL(finalize_kernel, dim3(1), dim3(256), 0, stream,
                       per_term, corr_flag, prob, thr, out);
}

// Round 4
// 99.310 us; speedup vs baseline: 1.7417x; 1.7417x over previous
//
#include <hip/hip_runtime.h>
#include <hip/hip_bf16.h>
#include <stdint.h>

typedef _Float16 half8 __attribute__((ext_vector_type(8)));
typedef _Float16 half4 __attribute__((ext_vector_type(4)));
typedef float f32x4 __attribute__((ext_vector_type(4)));
typedef unsigned long long u64;

#define N_ROWS 4096
#define DIM 1024
#define KCLS 32
#define MARGIN_F 0.3f
#define SENTN 0xFFFFFFFFFFFFFFFFull

// ---------------- global -> LDS direct staging (16B per lane) ----------------
typedef const __attribute__((address_space(1))) void GASV;
typedef __attribute__((address_space(3))) void LASV;

__device__ __forceinline__ void gload_lds16(const void* g, void* l) {
    __builtin_amdgcn_global_load_lds((GASV*)g, (LASV*)l, 16, 0, 0);
}

// ---------------- prep: sq, f16 convert, prediction argmax ----------------
__global__ __launch_bounds__(256) void prep_kernel(
    const float* __restrict__ inputs, const float* __restrict__ prediction,
    _Float16* __restrict__ xh, float* __restrict__ sq, int* __restrict__ pred_cls)
{
    int wid = threadIdx.x >> 6, lane = threadIdx.x & 63;
    int r = blockIdx.x * 4 + wid;
    const float* row = inputs + (size_t)r * DIM;
    _Float16* hrow = xh + (size_t)r * DIM;
    float s = 0.f;
#pragma unroll
    for (int c = 0; c < 4; ++c) {
        int idx = lane * 4 + c * 256;
        float4 v = *(const float4*)(row + idx);
        s += v.x * v.x + v.y * v.y + v.z * v.z + v.w * v.w;
        half4 h;
        h.x = (_Float16)v.x; h.y = (_Float16)v.y;
        h.z = (_Float16)v.z; h.w = (_Float16)v.w;
        *(half4*)(hrow + idx) = h;
    }
#pragma unroll
    for (int off = 32; off; off >>= 1) s += __shfl_xor(s, off);

    u64 key = 0ull;
    if (lane < KCLS) {
        unsigned b = __float_as_uint(prediction[(size_t)r * KCLS + lane]);
        unsigned u = (b & 0x80000000u) ? ~b : (b | 0x80000000u);
        key = ((u64)u << 32) | (unsigned)(KCLS - 1 - lane);
    }
#pragma unroll
    for (int off = 32; off; off >>= 1) {
        u64 o = __shfl_xor(key, off);
        if (o > key) key = o;
    }
    if (lane == 0) {
        sq[r] = s;
        pred_cls[r] = KCLS - 1 - (int)(key & 0xFFFFFFFFu);
    }
}

// ---------------- f16 MFMA GEMM ----------------
__global__ __launch_bounds__(256) void gemm_kernel(
    const _Float16* __restrict__ X, float* __restrict__ out, int rb0)
{
    __shared__ __align__(16) _Float16 As[128 * 32];
    __shared__ __align__(16) _Float16 Bs[128 * 32];
    int tid = threadIdx.x;
    int bx = blockIdx.x, by = blockIdx.y;
    int srow = tid >> 2;
    int scol = (tid & 3) * 8;
    const _Float16* gA0 = X + (size_t)(rb0 + bx * 128 + srow) * DIM + scol;
    const _Float16* gB0 = X + (size_t)(by * 128 + srow) * DIM + scol;
    const _Float16* gA1 = gA0 + (size_t)64 * DIM;
    const _Float16* gB1 = gB0 + (size_t)64 * DIM;
    _Float16* lA0 = As + tid * 8;
    _Float16* lA1 = As + 64 * 32 + tid * 8;
    _Float16* lB0 = Bs + tid * 8;
    _Float16* lB1 = Bs + 64 * 32 + tid * 8;

    int wid = tid >> 6, lane = tid & 63;
    int wr = (wid >> 1) * 64, wc = (wid & 1) * 64;
    int fr = lane & 15, fk = (lane >> 4) * 8;

    f32x4 acc[4][4];
#pragma unroll
    for (int m = 0; m < 4; ++m)
#pragma unroll
        for (int n = 0; n < 4; ++n) acc[m][n] = (f32x4){0.f, 0.f, 0.f, 0.f};

    for (int k0 = 0; k0 < DIM; k0 += 32) {
        gload_lds16(gA0 + k0, lA0);
        gload_lds16(gA1 + k0, lA1);
        gload_lds16(gB0 + k0, lB0);
        gload_lds16(gB1 + k0, lB1);
        __syncthreads();
        half8 a[4], b[4];
#pragma unroll
        for (int m = 0; m < 4; ++m) a[m] = *(const half8*)(As + (wr + m * 16 + fr) * 32 + fk);
#pragma unroll
        for (int n = 0; n < 4; ++n) b[n] = *(const half8*)(Bs + (wc + n * 16 + fr) * 32 + fk);
#pragma unroll
        for (int m = 0; m < 4; ++m)
#pragma unroll
            for (int n = 0; n < 4; ++n)
                acc[m][n] = __builtin_amdgcn_mfma_f32_16x16x32_f16(a[m], b[n], acc[m][n], 0, 0, 0);
        __syncthreads();
    }
    int orow_base = bx * 128 + wr + (lane >> 4) * 4;
    int ocol_base = by * 128 + wc + fr;
#pragma unroll
    for (int m = 0; m < 4; ++m)
#pragma unroll
        for (int n = 0; n < 4; ++n)
#pragma unroll
            for (int q = 0; q < 4; ++q)
                out[(size_t)(orow_base + m * 16 + q) * N_ROWS + (ocol_base + n * 16)] = acc[m][n][q];
}

// ---------------- per-row selection: reg scan + prune + bitonic top-k ----------------
// one block (256 thr) per row; thread t owns cols {q*1024 + t*4 + e}
__global__ __launch_bounds__(256) void select_kernel(
    const float* __restrict__ dot, const float* __restrict__ sq,
    const int* __restrict__ targets, const float* __restrict__ prob,
    const int* __restrict__ pred_cls, const float* __restrict__ thr_p,
    int rb0, float* __restrict__ per_term, int* __restrict__ corr_flag)
{
    __shared__ u64 Tn[4], Tp[4];
    __shared__ u64 negCand[64];
    __shared__ u64 posCand[64];
    __shared__ unsigned cnts[2];
    __shared__ u64 sN[12], sP[7];
    __shared__ u64 red[4];
    __shared__ u64 bcast;

    int t = threadIdx.x, lane = t & 63, w = t >> 6;
    int rloc = blockIdx.x, r = rb0 + rloc;
    int tr = targets[r];
    float sqr = sq[r];
    const float* drow = dot + (size_t)rloc * N_ROWS;

    if (t < 64) { negCand[t] = SENTN; posCand[t] = 0ull; }
    if (t < 2) cnts[t] = 0u;

    // ---- phase 1: vector scan, 16 keys in registers ----
    unsigned bits[16];
    unsigned maskSame = 0;
    u64 mneg = SENTN, mpos = 0ull;
#pragma unroll
    for (int q = 0; q < 4; ++q) {
        int col0 = q * 1024 + t * 4;
        float4 dv = *(const float4*)(drow + col0);
        float4 sv = *(const float4*)(sq + col0);
        int4 tv = *(const int4*)(targets + col0);
        float d2;
        unsigned b;
        int j = q * 4;
        d2 = fmaxf(sqr + sv.x - 2.f * dv.x, 1e-12f); b = __float_as_uint(d2); bits[j + 0] = b;
        if (tv.x == tr) { maskSame |= 1u << (j + 0);
            u64 pk = ((u64)b << 32) | (unsigned)(N_ROWS - 1 - (col0 + 0)); mpos = pk > mpos ? pk : mpos;
        } else { u64 nk = ((u64)b << 32) | (unsigned)(col0 + 0); mneg = nk < mneg ? nk : mneg; }
        d2 = fmaxf(sqr + sv.y - 2.f * dv.y, 1e-12f); b = __float_as_uint(d2); bits[j + 1] = b;
        if (tv.y == tr) { maskSame |= 1u << (j + 1);
            u64 pk = ((u64)b << 32) | (unsigned)(N_ROWS - 1 - (col0 + 1)); mpos = pk > mpos ? pk : mpos;
        } else { u64 nk = ((u64)b << 32) | (unsigned)(col0 + 1); mneg = nk < mneg ? nk : mneg; }
        d2 = fmaxf(sqr + sv.z - 2.f * dv.z, 1e-12f); b = __float_as_uint(d2); bits[j + 2] = b;
        if (tv.z == tr) { maskSame |= 1u << (j + 2);
            u64 pk = ((u64)b << 32) | (unsigned)(N_ROWS - 1 - (col0 + 2)); mpos = pk > mpos ? pk : mpos;
        } else { u64 nk = ((u64)b << 32) | (unsigned)(col0 + 2); mneg = nk < mneg ? nk : mneg; }
        d2 = fmaxf(sqr + sv.w - 2.f * dv.w, 1e-12f); b = __float_as_uint(d2); bits[j + 3] = b;
        if (tv.w == tr) { maskSame |= 1u << (j + 3);
            u64 pk = ((u64)b << 32) | (unsigned)(N_ROWS - 1 - (col0 + 3)); mpos = pk > mpos ? pk : mpos;
        } else { u64 nk = ((u64)b << 32) | (unsigned)(col0 + 3); mneg = nk < mneg ? nk : mneg; }
    }

    // ---- phase 2: per-wave 3rd-smallest (neg) / 2nd-largest (pos) ----
    u64 T3 = SENTN, m = mneg;
#pragma unroll
    for (int rd = 0; rd < 3; ++rd) {
        u64 b = m;
#pragma unroll
        for (int off = 32; off; off >>= 1) {
            u64 o = __shfl_xor(b, off);
            b = o < b ? o : b;
        }
        T3 = b;
        if (m == b) m = SENTN;
    }
    u64 P2 = 0ull, mp = mpos;
#pragma unroll
    for (int rd = 0; rd < 2; ++rd) {
        u64 b = mp;
#pragma unroll
        for (int off = 32; off; off >>= 1) {
            u64 o = __shfl_xor(b, off);
            b = o > b ? o : b;
        }
        P2 = b;
        if (mp == b) mp = 0ull;
    }
    if (lane == 0) { Tn[w] = T3; Tp[w] = P2; }
    __syncthreads();

    u64 Tneg = Tn[0];
    Tneg = Tn[1] > Tneg ? Tn[1] : Tneg;
    Tneg = Tn[2] > Tneg ? Tn[2] : Tneg;
    Tneg = Tn[3] > Tneg ? Tn[3] : Tneg;
    u64 Tpos = Tp[0];
    Tpos = Tp[1] < Tpos ? Tp[1] : Tpos;
    Tpos = Tp[2] < Tpos ? Tp[2] : Tpos;
    Tpos = Tp[3] < Tpos ? Tp[3] : Tpos;
    unsigned TnB = (unsigned)(Tneg >> 32);
    unsigned TpB = (unsigned)(Tpos >> 32);

    // ---- phase 3: append survivors (bits-only compare = superset, still exact) ----
#pragma unroll
    for (int q = 0; q < 4; ++q) {
#pragma unroll
        for (int e = 0; e < 4; ++e) {
            int j = q * 4 + e;
            int col = q * 1024 + t * 4 + e;
            unsigned b = bits[j];
            bool same = (maskSame >> j) & 1u;
            if (!same && b <= TnB) {
                unsigned s = atomicAdd(&cnts[0], 1u);
                if (s < 64u) negCand[s] = ((u64)b << 32) | (unsigned)col;
            }
            if (same && b >= TpB) {
                unsigned s = atomicAdd(&cnts[1], 1u);
                if (s < 64u) posCand[s] = ((u64)b << 32) | (unsigned)(N_ROWS - 1 - col);
            }
        }
    }
    __syncthreads();

    bool fb = (cnts[0] > 64u) || (cnts[1] > 64u);

    if (!fb) {
        // ---- phase 4: 64-lane bitonic sort; wave0 = neg asc, wave1 = pos desc ----
        if (w == 0) {
            u64 v = negCand[lane];
#pragma unroll
            for (int k = 2; k <= 64; k <<= 1) {
#pragma unroll
                for (int j = 32; j; j >>= 1) {
                    if (j >= k) continue;
                    u64 o = __shfl_xor(v, j);
                    bool up = (lane & k) == 0;
                    bool small = (lane & j) == 0;
                    bool keepmin = (small == up);
                    u64 lo = v < o ? v : o, hi = v < o ? o : v;
                    v = keepmin ? lo : hi;
                }
            }
            if (lane < 12) sN[lane] = v;
        } else if (w == 1) {
            u64 v = ~posCand[lane];           // ascending of ~pk == descending of pk
#pragma unroll
            for (int k = 2; k <= 64; k <<= 1) {
#pragma unroll
                for (int j = 32; j; j >>= 1) {
                    if (j >= k) continue;
                    u64 o = __shfl_xor(v, j);
                    bool up = (lane & k) == 0;
                    bool small = (lane & j) == 0;
                    bool keepmin = (small == up);
                    u64 lo = v < o ? v : o, hi = v < o ? o : v;
                    v = keepmin ? lo : hi;
                }
            }
            if (lane < 7) sP[lane] = ~v;
        }
    } else {
        // ---- exact fallback over register keys (degenerate data only) ----
        unsigned remN = 0, remP = 0;
        for (int rd = 0; rd < 12; ++rd) {
            u64 best = SENTN;
#pragma unroll
            for (int q = 0; q < 4; ++q)
#pragma unroll
                for (int e = 0; e < 4; ++e) {
                    int j = q * 4 + e;
                    int col = q * 1024 + t * 4 + e;
                    bool valid = !((maskSame >> j) & 1u) && !((remN >> j) & 1u);
                    u64 nk = valid ? (((u64)bits[j] << 32) | (unsigned)col) : SENTN;
                    best = nk < best ? nk : best;
                }
#pragma unroll
            for (int off = 32; off; off >>= 1) {
                u64 o = __shfl_xor(best, off);
                best = o < best ? o : best;
            }
            if (lane == 0) red[w] = best;
            __syncthreads();
            if (t == 0) {
                u64 b0 = red[0];
                b0 = red[1] < b0 ? red[1] : b0;
                b0 = red[2] < b0 ? red[2] : b0;
                b0 = red[3] < b0 ? red[3] : b0;
                sN[rd] = b0; bcast = b0;
            }
            __syncthreads();
            u64 b0 = bcast;
#pragma unroll
            for (int q = 0; q < 4; ++q)
#pragma unroll
                for (int e = 0; e < 4; ++e) {
                    int j = q * 4 + e;
                    int col = q * 1024 + t * 4 + e;
                    if ((((u64)bits[j] << 32) | (unsigned)col) == b0) remN |= 1u << j;
                }
            __syncthreads();
        }
        for (int rd = 0; rd < 7; ++rd) {
            u64 best = 0ull;
#pragma unroll
            for (int q = 0; q < 4; ++q)
#pragma unroll
                for (int e = 0; e < 4; ++e) {
                    int j = q * 4 + e;
                    int col = q * 1024 + t * 4 + e;
                    bool valid = ((maskSame >> j) & 1u) && !((remP >> j) & 1u);
                    u64 pk = valid ? (((u64)bits[j] << 32) | (unsigned)(N_ROWS - 1 - col)) : 0ull;
                    best = pk > best ? pk : best;
                }
#pragma unroll
            for (int off = 32; off; off >>= 1) {
                u64 o = __shfl_xor(best, off);
                best = o > best ? o : best;
            }
            if (lane == 0) red[w] = best;
            __syncthreads();
            if (t == 0) {
                u64 b0 = red[0];
                b0 = red[1] > b0 ? red[1] : b0;
                b0 = red[2] > b0 ? red[2] : b0;
                b0 = red[3] > b0 ? red[3] : b0;
                sP[rd] = b0; bcast = b0;
            }
            __syncthreads();
            u64 b0 = bcast;
#pragma unroll
            for (int q = 0; q < 4; ++q)
#pragma unroll
                for (int e = 0; e < 4; ++e) {
                    int j = q * 4 + e;
                    int col = q * 1024 + t * 4 + e;
                    if ((((u64)bits[j] << 32) | (unsigned)(N_ROWS - 1 - col)) == b0) remP |= 1u << j;
                }
            __syncthreads();
        }
    }
    __syncthreads();

    // ---- phase 5: lane-parallel epilogue on wave 0 ----
    if (w == 0) {
        float thr = *thr_p;
        u64 kN = (lane < 12) ? sN[lane] : SENTN;
        u64 kP = (lane >= 32 && lane < 39) ? sP[lane - 32] : 0ull;
        int idxN = ((int)(kN & 0xFFFFFFFFull)) & (N_ROWS - 1);
        int idxP = (N_ROWS - 1 - (int)(kP & 0xFFFFFFFFull)) & (N_ROWS - 1);
        bool confN = (lane < 12) && kN != SENTN && (prob[idxN] >= thr);
        bool confP = (lane >= 32 && lane < 39) && kP != 0ull && (prob[idxP] >= thr);
        u64 balN = __ballot(confN);
        u64 balP = __ballot(confP);

        u64 mN_ = balN & 0x7FEull;                 // lanes 1..10
        int selN = mN_ ? (__ffsll(mN_) - 1) : 11;
        unsigned dnn_bits = __shfl((unsigned)(kN >> 32), selN);
        u64 mP_ = balP & (0x3Eull << 32);          // lanes 33..37
        int selP = mP_ ? (__ffsll(mP_) - 1) : 38;
        unsigned dnp_bits = __shfl((unsigned)(kP >> 32), selP);
        unsigned dap_bits = __shfl((unsigned)(kP >> 32), 32);

        if (lane == 0) {
            float d_ap = sqrtf(__uint_as_float(dap_bits));
            float d_an = sqrtf(__uint_as_float((unsigned)(kN >> 32)));
            int hn = idxN;
            bool cp = (balP >> 32) & 1ull;
            bool cn = balN & 1ull;
            bool fn = (pred_cls[hn] == tr);
            float d_nn = sqrtf(__uint_as_float(dnn_bits));
            float d_np = sqrtf(__uint_as_float(dnp_bits));

            float e1p = __expf(d_ap), e2p = __expf(d_an);
            float w1 = (e1p * d_ap + e2p * d_an) / (e1p + e2p);
            float e1n = __expf(-d_ap), e2n = __expf(-d_an);
            float w0 = (e1n * d_ap + e2n * d_an) / (e1n + e2n + 1e-6f);
            bool case_b = cp && !cn && fn;
            bool case_cd = !cp && (cn || !fn);
            bool inv = !cp && !cn && fn;
            float ap = case_b ? w1 : (case_cd ? d_np : d_ap);
            float an = case_b ? d_nn : (case_cd ? w0 : d_an);
            float per = inv ? fmaxf(an - ap + MARGIN_F, 0.f)
                            : fmaxf(ap - an + MARGIN_F, 0.f);
            per_term[r] = per;
            corr_flag[r] = (an >= ap) ? 1 : 0;
        }
    }
}

// ---------------- final deterministic reduction ----------------
__global__ __launch_bounds__(256) void finalize_kernel(
    const float* __restrict__ per_term, const int* __restrict__ corr_flag,
    const float* __restrict__ prob, const float* __restrict__ thr_p,
    float* __restrict__ out)
{
    __shared__ float sred[4]; __shared__ int cred[4]; __shared__ int nred[4];
    float thr = *thr_p;
    int t = threadIdx.x, lane = t & 63, wid = t >> 6;
    float s = 0.f; int c = 0, n = 0;
    for (int i = t; i < N_ROWS; i += 256) {
        if (prob[i] >= thr) {
            s += per_term[i];
            c += corr_flag[i];
            n += 1;
        }
    }
#pragma unroll
    for (int off = 32; off; off >>= 1) {
        s += __shfl_xor(s, off);
        c += __shfl_xor(c, off);
        n += __shfl_xor(n, off);
    }
    if (lane == 0) { sred[wid] = s; cred[wid] = c; nred[wid] = n; }
    __syncthreads();
    if (t == 0) {
        float ss = sred[0] + sred[1] + sred[2] + sred[3];
        int cc = cred[0] + cred[1] + cred[2] + cred[3];
        int nn = nred[0] + nred[1] + nred[2] + nred[3];
        float loss = (nn > 0) ? ss / (float)nn : 0.f;
        out[0] = loss;
        out[1] = (float)cc;
        out[2] = (float)nn;
    }
}

// ---------------- launch ----------------
extern "C" void kernel_launch(void* const* d_in, const int* in_sizes, int n_in,
                              void* d_out, int out_size, void* d_ws, size_t ws_size,
                              hipStream_t stream)
{
    const float* inputs     = (const float*)d_in[0];
    const float* prediction = (const float*)d_in[1];
    const int*   targets    = (const int*)d_in[2];
    const float* prob       = (const float*)d_in[4];
    const float* thr        = (const float*)d_in[5];
    float* out = (float*)d_out;

    char* ws = (char*)d_ws;
    size_t off = 0;
    auto alloc = [&](size_t bytes) -> char* {
        char* p = ws + off;
        off = (off + bytes + 255) & ~(size_t)255;
        return p;
    };
    _Float16* xh     = (_Float16*)alloc((size_t)N_ROWS * DIM * sizeof(_Float16));
    float* sq        = (float*)alloc((size_t)N_ROWS * 4);
    int*   pred_cls  = (int*)alloc((size_t)N_ROWS * 4);
    float* per_term  = (float*)alloc((size_t)N_ROWS * 4);
    int*   corr_flag = (int*)alloc((size_t)N_ROWS * 4);

    size_t avail = (ws_size > off) ? (ws_size - off) : 0;
    size_t rowbytes = (size_t)N_ROWS * 4;
    int RB = 128;
    while (RB * 2 <= N_ROWS && (size_t)(RB * 2) * rowbytes <= avail) RB *= 2;
    float* dotbuf = (float*)alloc((size_t)RB * rowbytes);

    hipLaunchKernelGGL(prep_kernel, dim3(N_ROWS / 4), dim3(256), 0, stream,
                       inputs, prediction, xh, sq, pred_cls);
    for (int rb0 = 0; rb0 < N_ROWS; rb0 += RB) {
        hipLaunchKernelGGL(gemm_kernel, dim3(RB / 128, N_ROWS / 128), dim3(256), 0, stream,
                           xh, dotbuf, rb0);
        hipLaunchKernelGGL(select_kernel, dim3(RB), dim3(256), 0, stream,
                           dotbuf, sq, targets, prob, pred_cls, thr, rb0,
                           per_term, corr_flag);
    }
    hipLaunchKernelGGL(finalize_kernel, dim3(1), dim3(256), 0, stream,
                       per_term, corr_flag, prob, thr, out);
}

// Round 5
// 94.037 us; speedup vs baseline: 1.8393x; 1.0561x over previous
//
#include <hip/hip_runtime.h>
#include <hip/hip_bf16.h>
#include <stdint.h>

typedef _Float16 half8 __attribute__((ext_vector_type(8)));
typedef _Float16 half4 __attribute__((ext_vector_type(4)));
typedef float f32x4 __attribute__((ext_vector_type(4)));
typedef unsigned long long u64;

#define N_ROWS 4096
#define DIM 1024
#define KCLS 32
#define MARGIN_F 0.3f
#define SENTN 0xFFFFFFFFFFFFFFFFull

// ---------------- global -> LDS direct staging (16B per lane) ----------------
typedef const __attribute__((address_space(1))) void GASV;
typedef __attribute__((address_space(3))) void LASV;

__device__ __forceinline__ void gload_lds16(const void* g, void* l) {
    __builtin_amdgcn_global_load_lds((GASV*)g, (LASV*)l, 16, 0, 0);
}

// ---------------- prep: sq, f16 convert, prediction argmax ----------------
__global__ __launch_bounds__(256) void prep_kernel(
    const float* __restrict__ inputs, const float* __restrict__ prediction,
    _Float16* __restrict__ xh, float* __restrict__ sq, int* __restrict__ pred_cls)
{
    int wid = threadIdx.x >> 6, lane = threadIdx.x & 63;
    int r = blockIdx.x * 4 + wid;
    const float* row = inputs + (size_t)r * DIM;
    _Float16* hrow = xh + (size_t)r * DIM;
    float s = 0.f;
#pragma unroll
    for (int c = 0; c < 4; ++c) {
        int idx = lane * 4 + c * 256;
        float4 v = *(const float4*)(row + idx);
        s += v.x * v.x + v.y * v.y + v.z * v.z + v.w * v.w;
        half4 h;
        h.x = (_Float16)v.x; h.y = (_Float16)v.y;
        h.z = (_Float16)v.z; h.w = (_Float16)v.w;
        *(half4*)(hrow + idx) = h;
    }
#pragma unroll
    for (int off = 32; off; off >>= 1) s += __shfl_xor(s, off);

    u64 key = 0ull;
    if (lane < KCLS) {
        unsigned b = __float_as_uint(prediction[(size_t)r * KCLS + lane]);
        unsigned u = (b & 0x80000000u) ? ~b : (b | 0x80000000u);
        key = ((u64)u << 32) | (unsigned)(KCLS - 1 - lane);
    }
#pragma unroll
    for (int off = 32; off; off >>= 1) {
        u64 o = __shfl_xor(key, off);
        if (o > key) key = o;
    }
    if (lane == 0) {
        sq[r] = s;
        pred_cls[r] = KCLS - 1 - (int)(key & 0xFFFFFFFFu);
    }
}

// ---------------- f16 MFMA GEMM: 128x128 tile, BK=64, XOR-swizzled LDS ----------------
// LDS rows are 128 B (8 slots of 16 B); content slot s holds global slot s^(row&7).
// global_load_lds writes linearly; source address carries the inverse swizzle.
__global__ __launch_bounds__(256) void gemm_kernel(
    const _Float16* __restrict__ X, float* __restrict__ out, int rb0)
{
    __shared__ __align__(16) _Float16 As[128 * 64];
    __shared__ __align__(16) _Float16 Bs[128 * 64];
    int tid = threadIdx.x;

    // bijective XCD swizzle: 1024 blocks, 8 XCDs, 128 consecutive per XCD
    int wg = blockIdx.x;
    int swz = (wg & 7) * 128 + (wg >> 3);
    int bx = swz & 31, by = swz >> 5;

    // staging map: round p, thread t stages LDS bytes [p*4096 + t*16, +16)
    //   = row (p*32 + (t>>3)), slot (t&7); source = global slot (t&7)^((t>>3)&7)
    int rs = tid >> 3;           // 0..31
    int ss = tid & 7;            // 0..7
    int srcslot = ss ^ (rs & 7);
    const _Float16* gA = X + (size_t)(rb0 + bx * 128 + rs) * DIM + srcslot * 8;
    const _Float16* gB = X + (size_t)(by * 128 + rs) * DIM + srcslot * 8;
    _Float16* lA = As + tid * 8;
    _Float16* lB = Bs + tid * 8;

    int wid = tid >> 6, lane = tid & 63;
    int wr = (wid >> 1) * 64, wc = (wid & 1) * 64;
    int fr = lane & 15, q4 = lane >> 4;

    f32x4 acc[4][4];
#pragma unroll
    for (int m = 0; m < 4; ++m)
#pragma unroll
        for (int n = 0; n < 4; ++n) acc[m][n] = (f32x4){0.f, 0.f, 0.f, 0.f};

    for (int k0 = 0; k0 < DIM; k0 += 64) {
#pragma unroll
        for (int p = 0; p < 4; ++p) {
            gload_lds16(gA + k0 + (size_t)(p * 32) * DIM, lA + p * 2048);
            gload_lds16(gB + k0 + (size_t)(p * 32) * DIM, lB + p * 2048);
        }
        __syncthreads();
#pragma unroll
        for (int ks = 0; ks < 2; ++ks) {
            half8 a[4], b[4];
#pragma unroll
            for (int m = 0; m < 4; ++m) {
                int row = wr + m * 16 + fr;
                int s = (ks * 4 + q4) ^ (row & 7);
                a[m] = *(const half8*)(As + row * 64 + s * 8);
            }
#pragma unroll
            for (int n = 0; n < 4; ++n) {
                int row = wc + n * 16 + fr;
                int s = (ks * 4 + q4) ^ (row & 7);
                b[n] = *(const half8*)(Bs + row * 64 + s * 8);
            }
#pragma unroll
            for (int m = 0; m < 4; ++m)
#pragma unroll
                for (int n = 0; n < 4; ++n)
                    acc[m][n] = __builtin_amdgcn_mfma_f32_16x16x32_f16(a[m], b[n], acc[m][n], 0, 0, 0);
        }
        __syncthreads();
    }
    int orow_base = bx * 128 + wr + q4 * 4;
    int ocol_base = by * 128 + wc + fr;
#pragma unroll
    for (int m = 0; m < 4; ++m)
#pragma unroll
        for (int n = 0; n < 4; ++n)
#pragma unroll
            for (int q = 0; q < 4; ++q)
                out[(size_t)(orow_base + m * 16 + q) * N_ROWS + (ocol_base + n * 16)] = acc[m][n][q];
}

// ---------------- per-row selection: reg scan + prune + bitonic top-k ----------------
__global__ __launch_bounds__(256) void select_kernel(
    const float* __restrict__ dot, const float* __restrict__ sq,
    const int* __restrict__ targets, const float* __restrict__ prob,
    const int* __restrict__ pred_cls, const float* __restrict__ thr_p,
    int rb0, float* __restrict__ per_term, int* __restrict__ corr_flag)
{
    __shared__ u64 Tn[4], Tp[4];
    __shared__ u64 negCand[64];
    __shared__ u64 posCand[64];
    __shared__ unsigned cnts[2];
    __shared__ u64 sN[12], sP[7];
    __shared__ u64 red[4];
    __shared__ u64 bcast;

    int t = threadIdx.x, lane = t & 63, w = t >> 6;
    int rloc = blockIdx.x, r = rb0 + rloc;
    int tr = targets[r];
    float sqr = sq[r];
    const float* drow = dot + (size_t)rloc * N_ROWS;

    if (t < 64) { negCand[t] = SENTN; posCand[t] = 0ull; }
    if (t < 2) cnts[t] = 0u;

    unsigned bits[16];
    unsigned maskSame = 0;
    u64 mneg = SENTN, mpos = 0ull;
#pragma unroll
    for (int q = 0; q < 4; ++q) {
        int col0 = q * 1024 + t * 4;
        float4 dv = *(const float4*)(drow + col0);
        float4 sv = *(const float4*)(sq + col0);
        int4 tv = *(const int4*)(targets + col0);
        float d2;
        unsigned b;
        int j = q * 4;
        d2 = fmaxf(sqr + sv.x - 2.f * dv.x, 1e-12f); b = __float_as_uint(d2); bits[j + 0] = b;
        if (tv.x == tr) { maskSame |= 1u << (j + 0);
            u64 pk = ((u64)b << 32) | (unsigned)(N_ROWS - 1 - (col0 + 0)); mpos = pk > mpos ? pk : mpos;
        } else { u64 nk = ((u64)b << 32) | (unsigned)(col0 + 0); mneg = nk < mneg ? nk : mneg; }
        d2 = fmaxf(sqr + sv.y - 2.f * dv.y, 1e-12f); b = __float_as_uint(d2); bits[j + 1] = b;
        if (tv.y == tr) { maskSame |= 1u << (j + 1);
            u64 pk = ((u64)b << 32) | (unsigned)(N_ROWS - 1 - (col0 + 1)); mpos = pk > mpos ? pk : mpos;
        } else { u64 nk = ((u64)b << 32) | (unsigned)(col0 + 1); mneg = nk < mneg ? nk : mneg; }
        d2 = fmaxf(sqr + sv.z - 2.f * dv.z, 1e-12f); b = __float_as_uint(d2); bits[j + 2] = b;
        if (tv.z == tr) { maskSame |= 1u << (j + 2);
            u64 pk = ((u64)b << 32) | (unsigned)(N_ROWS - 1 - (col0 + 2)); mpos = pk > mpos ? pk : mpos;
        } else { u64 nk = ((u64)b << 32) | (unsigned)(col0 + 2); mneg = nk < mneg ? nk : mneg; }
        d2 = fmaxf(sqr + sv.w - 2.f * dv.w, 1e-12f); b = __float_as_uint(d2); bits[j + 3] = b;
        if (tv.w == tr) { maskSame |= 1u << (j + 3);
            u64 pk = ((u64)b << 32) | (unsigned)(N_ROWS - 1 - (col0 + 3)); mpos = pk > mpos ? pk : mpos;
        } else { u64 nk = ((u64)b << 32) | (unsigned)(col0 + 3); mneg = nk < mneg ? nk : mneg; }
    }

    u64 T3 = SENTN, m = mneg;
#pragma unroll
    for (int rd = 0; rd < 3; ++rd) {
        u64 b = m;
#pragma unroll
        for (int off = 32; off; off >>= 1) {
            u64 o = __shfl_xor(b, off);
            b = o < b ? o : b;
        }
        T3 = b;
        if (m == b) m = SENTN;
    }
    u64 P2 = 0ull, mp = mpos;
#pragma unroll
    for (int rd = 0; rd < 2; ++rd) {
        u64 b = mp;
#pragma unroll
        for (int off = 32; off; off >>= 1) {
            u64 o = __shfl_xor(b, off);
            b = o > b ? o : b;
        }
        P2 = b;
        if (mp == b) mp = 0ull;
    }
    if (lane == 0) { Tn[w] = T3; Tp[w] = P2; }
    __syncthreads();

    u64 Tneg = Tn[0];
    Tneg = Tn[1] > Tneg ? Tn[1] : Tneg;
    Tneg = Tn[2] > Tneg ? Tn[2] : Tneg;
    Tneg = Tn[3] > Tneg ? Tn[3] : Tneg;
    u64 Tpos = Tp[0];
    Tpos = Tp[1] < Tpos ? Tp[1] : Tpos;
    Tpos = Tp[2] < Tpos ? Tp[2] : Tpos;
    Tpos = Tp[3] < Tpos ? Tp[3] : Tpos;
    unsigned TnB = (unsigned)(Tneg >> 32);
    unsigned TpB = (unsigned)(Tpos >> 32);

#pragma unroll
    for (int q = 0; q < 4; ++q) {
#pragma unroll
        for (int e = 0; e < 4; ++e) {
            int j = q * 4 + e;
            int col = q * 1024 + t * 4 + e;
            unsigned b = bits[j];
            bool same = (maskSame >> j) & 1u;
            if (!same && b <= TnB) {
                unsigned s = atomicAdd(&cnts[0], 1u);
                if (s < 64u) negCand[s] = ((u64)b << 32) | (unsigned)col;
            }
            if (same && b >= TpB) {
                unsigned s = atomicAdd(&cnts[1], 1u);
                if (s < 64u) posCand[s] = ((u64)b << 32) | (unsigned)(N_ROWS - 1 - col);
            }
        }
    }
    __syncthreads();

    bool fb = (cnts[0] > 64u) || (cnts[1] > 64u);

    if (!fb) {
        if (w == 0) {
            u64 v = negCand[lane];
#pragma unroll
            for (int k = 2; k <= 64; k <<= 1) {
#pragma unroll
                for (int j = 32; j; j >>= 1) {
                    if (j >= k) continue;
                    u64 o = __shfl_xor(v, j);
                    bool up = (lane & k) == 0;
                    bool small = (lane & j) == 0;
                    bool keepmin = (small == up);
                    u64 lo = v < o ? v : o, hi = v < o ? o : v;
                    v = keepmin ? lo : hi;
                }
            }
            if (lane < 12) sN[lane] = v;
        } else if (w == 1) {
            u64 v = ~posCand[lane];
#pragma unroll
            for (int k = 2; k <= 64; k <<= 1) {
#pragma unroll
                for (int j = 32; j; j >>= 1) {
                    if (j >= k) continue;
                    u64 o = __shfl_xor(v, j);
                    bool up = (lane & k) == 0;
                    bool small = (lane & j) == 0;
                    bool keepmin = (small == up);
                    u64 lo = v < o ? v : o, hi = v < o ? o : v;
                    v = keepmin ? lo : hi;
                }
            }
            if (lane < 7) sP[lane] = ~v;
        }
    } else {
        unsigned remN = 0, remP = 0;
        for (int rd = 0; rd < 12; ++rd) {
            u64 best = SENTN;
#pragma unroll
            for (int q = 0; q < 4; ++q)
#pragma unroll
                for (int e = 0; e < 4; ++e) {
                    int j = q * 4 + e;
                    int col = q * 1024 + t * 4 + e;
                    bool valid = !((maskSame >> j) & 1u) && !((remN >> j) & 1u);
                    u64 nk = valid ? (((u64)bits[j] << 32) | (unsigned)col) : SENTN;
                    best = nk < best ? nk : best;
                }
#pragma unroll
            for (int off = 32; off; off >>= 1) {
                u64 o = __shfl_xor(best, off);
                best = o < best ? o : best;
            }
            if (lane == 0) red[w] = best;
            __syncthreads();
            if (t == 0) {
                u64 b0 = red[0];
                b0 = red[1] < b0 ? red[1] : b0;
                b0 = red[2] < b0 ? red[2] : b0;
                b0 = red[3] < b0 ? red[3] : b0;
                sN[rd] = b0; bcast = b0;
            }
            __syncthreads();
            u64 b0 = bcast;
#pragma unroll
            for (int q = 0; q < 4; ++q)
#pragma unroll
                for (int e = 0; e < 4; ++e) {
                    int j = q * 4 + e;
                    int col = q * 1024 + t * 4 + e;
                    if ((((u64)bits[j] << 32) | (unsigned)col) == b0) remN |= 1u << j;
                }
            __syncthreads();
        }
        for (int rd = 0; rd < 7; ++rd) {
            u64 best = 0ull;
#pragma unroll
            for (int q = 0; q < 4; ++q)
#pragma unroll
                for (int e = 0; e < 4; ++e) {
                    int j = q * 4 + e;
                    int col = q * 1024 + t * 4 + e;
                    bool valid = ((maskSame >> j) & 1u) && !((remP >> j) & 1u);
                    u64 pk = valid ? (((u64)bits[j] << 32) | (unsigned)(N_ROWS - 1 - col)) : 0ull;
                    best = pk > best ? pk : best;
                }
#pragma unroll
            for (int off = 32; off; off >>= 1) {
                u64 o = __shfl_xor(best, off);
                best = o > best ? o : best;
            }
            if (lane == 0) red[w] = best;
            __syncthreads();
            if (t == 0) {
                u64 b0 = red[0];
                b0 = red[1] > b0 ? red[1] : b0;
                b0 = red[2] > b0 ? red[2] : b0;
                b0 = red[3] > b0 ? red[3] : b0;
                sP[rd] = b0; bcast = b0;
            }
            __syncthreads();
            u64 b0 = bcast;
#pragma unroll
            for (int q = 0; q < 4; ++q)
#pragma unroll
                for (int e = 0; e < 4; ++e) {
                    int j = q * 4 + e;
                    int col = q * 1024 + t * 4 + e;
                    if ((((u64)bits[j] << 32) | (unsigned)(N_ROWS - 1 - col)) == b0) remP |= 1u << j;
                }
            __syncthreads();
        }
    }
    __syncthreads();

    if (w == 0) {
        float thr = *thr_p;
        u64 kN = (lane < 12) ? sN[lane] : SENTN;
        u64 kP = (lane >= 32 && lane < 39) ? sP[lane - 32] : 0ull;
        int idxN = ((int)(kN & 0xFFFFFFFFull)) & (N_ROWS - 1);
        int idxP = (N_ROWS - 1 - (int)(kP & 0xFFFFFFFFull)) & (N_ROWS - 1);
        bool confN = (lane < 12) && kN != SENTN && (prob[idxN] >= thr);
        bool confP = (lane >= 32 && lane < 39) && kP != 0ull && (prob[idxP] >= thr);
        u64 balN = __ballot(confN);
        u64 balP = __ballot(confP);

        u64 mN_ = balN & 0x7FEull;
        int selN = mN_ ? (__ffsll(mN_) - 1) : 11;
        unsigned dnn_bits = __shfl((unsigned)(kN >> 32), selN);
        u64 mP_ = balP & (0x3Eull << 32);
        int selP = mP_ ? (__ffsll(mP_) - 1) : 38;
        unsigned dnp_bits = __shfl((unsigned)(kP >> 32), selP);
        unsigned dap_bits = __shfl((unsigned)(kP >> 32), 32);

        if (lane == 0) {
            float d_ap = sqrtf(__uint_as_float(dap_bits));
            float d_an = sqrtf(__uint_as_float((unsigned)(kN >> 32)));
            int hn = idxN;
            bool cp = (balP >> 32) & 1ull;
            bool cn = balN & 1ull;
            bool fn = (pred_cls[hn] == tr);
            float d_nn = sqrtf(__uint_as_float(dnn_bits));
            float d_np = sqrtf(__uint_as_float(dnp_bits));

            float e1p = __expf(d_ap), e2p = __expf(d_an);
            float w1 = (e1p * d_ap + e2p * d_an) / (e1p + e2p);
            float e1n = __expf(-d_ap), e2n = __expf(-d_an);
            float w0 = (e1n * d_ap + e2n * d_an) / (e1n + e2n + 1e-6f);
            bool case_b = cp && !cn && fn;
            bool case_cd = !cp && (cn || !fn);
            bool inv = !cp && !cn && fn;
            float ap = case_b ? w1 : (case_cd ? d_np : d_ap);
            float an = case_b ? d_nn : (case_cd ? w0 : d_an);
            float per = inv ? fmaxf(an - ap + MARGIN_F, 0.f)
                            : fmaxf(ap - an + MARGIN_F, 0.f);
            per_term[r] = per;
            corr_flag[r] = (an >= ap) ? 1 : 0;
        }
    }
}

// ---------------- final deterministic reduction ----------------
__global__ __launch_bounds__(256) void finalize_kernel(
    const float* __restrict__ per_term, const int* __restrict__ corr_flag,
    const float* __restrict__ prob, const float* __restrict__ thr_p,
    float* __restrict__ out)
{
    __shared__ float sred[4]; __shared__ int cred[4]; __shared__ int nred[4];
    float thr = *thr_p;
    int t = threadIdx.x, lane = t & 63, wid = t >> 6;
    float s = 0.f; int c = 0, n = 0;
    for (int i = t; i < N_ROWS; i += 256) {
        if (prob[i] >= thr) {
            s += per_term[i];
            c += corr_flag[i];
            n += 1;
        }
    }
#pragma unroll
    for (int off = 32; off; off >>= 1) {
        s += __shfl_xor(s, off);
        c += __shfl_xor(c, off);
        n += __shfl_xor(n, off);
    }
    if (lane == 0) { sred[wid] = s; cred[wid] = c; nred[wid] = n; }
    __syncthreads();
    if (t == 0) {
        float ss = sred[0] + sred[1] + sred[2] + sred[3];
        int cc = cred[0] + cred[1] + cred[2] + cred[3];
        int nn = nred[0] + nred[1] + nred[2] + nred[3];
        float loss = (nn > 0) ? ss / (float)nn : 0.f;
        out[0] = loss;
        out[1] = (float)cc;
        out[2] = (float)nn;
    }
}

// ---------------- launch ----------------
extern "C" void kernel_launch(void* const* d_in, const int* in_sizes, int n_in,
                              void* d_out, int out_size, void* d_ws, size_t ws_size,
                              hipStream_t stream)
{
    const float* inputs     = (const float*)d_in[0];
    const float* prediction = (const float*)d_in[1];
    const int*   targets    = (const int*)d_in[2];
    const float* prob       = (const float*)d_in[4];
    const float* thr        = (const float*)d_in[5];
    float* out = (float*)d_out;

    char* ws = (char*)d_ws;
    size_t off = 0;
    auto alloc = [&](size_t bytes) -> char* {
        char* p = ws + off;
        off = (off + bytes + 255) & ~(size_t)255;
        return p;
    };
    _Float16* xh     = (_Float16*)alloc((size_t)N_ROWS * DIM * sizeof(_Float16));
    float* sq        = (float*)alloc((size_t)N_ROWS * 4);
    int*   pred_cls  = (int*)alloc((size_t)N_ROWS * 4);
    float* per_term  = (float*)alloc((size_t)N_ROWS * 4);
    int*   corr_flag = (int*)alloc((size_t)N_ROWS * 4);

    size_t avail = (ws_size > off) ? (ws_size - off) : 0;
    size_t rowbytes = (size_t)N_ROWS * 4;
    int RB = 128;
    while (RB * 2 <= N_ROWS && (size_t)(RB * 2) * rowbytes <= avail) RB *= 2;
    float* dotbuf = (float*)alloc((size_t)RB * rowbytes);

    hipLaunchKernelGGL(prep_kernel, dim3(N_ROWS / 4), dim3(256), 0, stream,
                       inputs, prediction, xh, sq, pred_cls);
    for (int rb0 = 0; rb0 < N_ROWS; rb0 += RB) {
        hipLaunchKernelGGL(gemm_kernel, dim3((RB / 128) * (N_ROWS / 128)), dim3(256), 0, stream,
                           xh, dotbuf, rb0);
        hipLaunchKernelGGL(select_kernel, dim3(RB), dim3(256), 0, stream,
                           dotbuf, sq, targets, prob, pred_cls, thr, rb0,
                           per_term, corr_flag);
    }
    hipLaunchKernelGGL(finalize_kernel, dim3(1), dim3(256), 0, stream,
                       per_term, corr_flag, prob, thr, out);
}